// Round 1
// baseline (25.230 us; speedup 1.0000x reference)
//
#include <hip/hip_runtime.h>

// Problem constants (from reference): B=8, S=2048, D=1024, fp32 in/out.
#define BB 8
#define SS 2048
#define DD 1024
#define CHUNKS 64                   // S split into 64 chunks of 32 rows
#define ROWS_PER_CHUNK (SS / CHUNKS) // 32

// ---------------------------------------------------------------------------
// Stage 1: partial[c][b][d] = sum over the 32 rows of chunk c of x[b, :, d]
// grid = B*CHUNKS = 512 blocks, 256 threads. Each iteration of the row loop
// reads one full 4 KiB row, perfectly coalesced (thread t -> float4 at col 4t).
// ---------------------------------------------------------------------------
__global__ __launch_bounds__(256) void colsum_partial(
    const float* __restrict__ x, float* __restrict__ partial) {
    const int blk = blockIdx.x;
    const int b = blk / CHUNKS;
    const int c = blk % CHUNKS;
    const int t = threadIdx.x;  // 0..255, handles float4 at column 4t

    const float4* xp = (const float4*)(x + (size_t)b * SS * DD
                                         + (size_t)c * ROWS_PER_CHUNK * DD);
    float4 acc = make_float4(0.f, 0.f, 0.f, 0.f);
#pragma unroll
    for (int r = 0; r < ROWS_PER_CHUNK; ++r) {
        float4 v = xp[(size_t)r * (DD / 4) + t];
        acc.x += v.x; acc.y += v.y; acc.z += v.z; acc.w += v.w;
    }
    float4* pp = (float4*)(partial + ((size_t)c * BB + b) * DD);
    pp[t] = acc;
}

// ---------------------------------------------------------------------------
// Stage 2: xs[i] = sum_c partial[c*8192 + i],  i = b*D+d in [0, 8192)
// grid = 32 blocks x 256 threads; reads are coalesced for every c.
// ---------------------------------------------------------------------------
__global__ __launch_bounds__(256) void colsum_reduce(
    const float* __restrict__ partial, float* __restrict__ xs) {
    const int i = blockIdx.x * 256 + threadIdx.x;  // 0..8191
    float acc = 0.f;
#pragma unroll 8
    for (int c = 0; c < CHUNKS; ++c) {
        acc += partial[(size_t)c * (BB * DD) + i];
    }
    xs[i] = acc;
}

// ---------------------------------------------------------------------------
// Stage 3: out[b, e] = sum_d xs[b, d] * Wv[e, d] + S * bv[e]
// grid = D = 1024 blocks (one per output feature e), 256 threads.
// Each block loads Wv[e,:] (4 KiB, coalesced float4) once; xs (32 KiB) is
// L2/L1-resident across blocks. Wave-shuffle + LDS block reduction.
// ---------------------------------------------------------------------------
__global__ __launch_bounds__(256) void gemv_out(
    const float* __restrict__ Wv, const float* __restrict__ bv,
    const float* __restrict__ xs, float* __restrict__ out) {
    const int e = blockIdx.x;
    const int t = threadIdx.x;
    const int lane = t & 63;
    const int wid = t >> 6;  // 4 waves

    const float4 w = ((const float4*)(Wv + (size_t)e * DD))[t];

    float acc[BB];
#pragma unroll
    for (int b = 0; b < BB; ++b) {
        float4 xv = ((const float4*)(xs + b * DD))[t];
        acc[b] = w.x * xv.x + w.y * xv.y + w.z * xv.z + w.w * xv.w;
    }

    __shared__ float lds[BB * 4];
#pragma unroll
    for (int b = 0; b < BB; ++b) {
        float v = acc[b];
#pragma unroll
        for (int off = 32; off > 0; off >>= 1) v += __shfl_down(v, off);
        if (lane == 0) lds[b * 4 + wid] = v;
    }
    __syncthreads();
    if (t < BB) {
        const float tot = lds[t * 4 + 0] + lds[t * 4 + 1]
                        + lds[t * 4 + 2] + lds[t * 4 + 3];
        out[(size_t)t * DD + e] = tot + (float)SS * bv[e];
    }
}

// ---------------------------------------------------------------------------
// Inputs (setup_inputs order): 0=x [B,S,D], 1=Wq, 2=bq, 3=Wk, 4=bk, 5=Wv, 6=bv
// Output: [B, D] fp32.  Identity used: softmax rows sum to 1 -> attention==1,
// so out = (sum_s x) @ Wv^T + S*bv.  Q/K/softmax are numerically irrelevant
// (error ~1e-4 << threshold).
// ---------------------------------------------------------------------------
extern "C" void kernel_launch(void* const* d_in, const int* in_sizes, int n_in,
                              void* d_out, int out_size, void* d_ws, size_t ws_size,
                              hipStream_t stream) {
    const float* x  = (const float*)d_in[0];
    const float* Wv = (const float*)d_in[5];
    const float* bv = (const float*)d_in[6];
    float* out = (float*)d_out;

    float* partial = (float*)d_ws;                       // CHUNKS*B*D floats = 2 MiB
    float* xs      = partial + (size_t)CHUNKS * BB * DD; // B*D floats = 32 KiB

    colsum_partial<<<BB * CHUNKS, 256, 0, stream>>>(x, partial);
    colsum_reduce<<<(BB * DD) / 256, 256, 0, stream>>>(partial, xs);
    gemv_out<<<DD, 256, 0, stream>>>(Wv, bv, xs, out);
}